// Round 3
// baseline (75.691 us; speedup 1.0000x reference)
//
#include <hip/hip_runtime.h>
#include <hip/hip_bf16.h>

#define B_  16
#define C_  64
#define HW  4096   // 64*64
#define KP  1024   // pooled positions (32*32)
#define LOG2E 1.44269504088896f

typedef short short8 __attribute__((ext_vector_type(8)));
typedef float floatx16 __attribute__((ext_vector_type(16)));

union Frag { uint4 u; short8 s; };

// ---- attn kernel LDS layout (bytes) ----
// G region [32][2064] = 66048 (main loop) UNIONED with ATTN [2][256][144] = 73728 (epilogue)
#define G_ROW      2064
#define ATTN_ROW   144
#define UNION_SZ   73728
#define WO_OFF     UNION_SZ            // [64][80B] = 5120, persistent
#define WO_ROW     80
#define L_OFF      (WO_OFF + 5120)     // [2][256] f32 = 2048
#define LDS_BYTES  (L_OFF + 2048)      // 80896

__device__ __forceinline__ unsigned cvt_pk_bf16(float lo, float hi) {
    unsigned r;
    asm("v_cvt_pk_bf16_f32 %0, %1, %2" : "=v"(r) : "v"(lo), "v"(hi));
    return r;
}
#define PLSWAP(a, b) asm("v_permlane32_swap_b32 %0, %1" : "+v"(a), "+v"(b))

// Build two PV A-operand fragments (K=16 each) from 16 lane-local P values.
__device__ __forceinline__ void build_pfrags(const float* p, Frag& f0, Frag& f1) {
    unsigned u0 = cvt_pk_bf16(p[0], p[1]);
    unsigned u1 = cvt_pk_bf16(p[2], p[3]);
    unsigned u2 = cvt_pk_bf16(p[4], p[5]);
    unsigned u3 = cvt_pk_bf16(p[6], p[7]);
    PLSWAP(u0, u2);
    PLSWAP(u1, u3);
    f0.u.x = u0; f0.u.y = u1; f0.u.z = u2; f0.u.w = u3;
    unsigned v0 = cvt_pk_bf16(p[8],  p[9]);
    unsigned v1 = cvt_pk_bf16(p[10], p[11]);
    unsigned v2 = cvt_pk_bf16(p[12], p[13]);
    unsigned v3 = cvt_pk_bf16(p[14], p[15]);
    PLSWAP(v0, v2);
    PLSWAP(v1, v3);
    f1.u.x = v0; f1.u.y = v1; f1.u.z = v2; f1.u.w = v3;
}

// ---------------------------------------------------------------------------
// Kernel A: fused 1x1 conv (48 oc = theta(8) ++ phi(8) ++ g(32)); theta stored
// full-res (x LOG2E, K-padded to 16 with zeros); phi/g maxpooled 2x2.
// Outputs: theta16[B][4096][16], phi16[B][1024][16] (K-padded), gT[B][32][1024].
// ---------------------------------------------------------------------------
__global__ __launch_bounds__(256) void convpool_kernel(
    const float* __restrict__ x,
    const float* __restrict__ w_theta,
    const float* __restrict__ w_phi,
    const float* __restrict__ w_g,
    __hip_bfloat16* __restrict__ theta16,
    __hip_bfloat16* __restrict__ phi16,
    __hip_bfloat16* __restrict__ gT)
{
    __shared__ float conv_lds[256 * 41];
    const int bi = blockIdx.x;
    const int b  = bi >> 4;
    const int rg = bi & 15;
    const int t  = threadIdx.x;

    const int q = rg * 256 + t;
    const float* xb = x + (size_t)b * C_ * HW + q;

    float acc[48];
    #pragma unroll
    for (int oc = 0; oc < 48; ++oc) acc[oc] = 0.f;

    #pragma unroll 8
    for (int c = 0; c < C_; ++c) {
        const float xv = xb[(size_t)c * HW];
        #pragma unroll
        for (int j = 0; j < 8; ++j)  acc[j]      += w_theta[j * C_ + c] * xv;
        #pragma unroll
        for (int j = 0; j < 8; ++j)  acc[8 + j]  += w_phi[j * C_ + c] * xv;
        #pragma unroll
        for (int j = 0; j < 32; ++j) acc[16 + j] += w_g[j * C_ + c] * xv;
    }

    // theta: direct store, LOG2E folded, upper 8 channels zero
    {
        uint4 u, z = {0u, 0u, 0u, 0u};
        u.x = cvt_pk_bf16(acc[0] * LOG2E, acc[1] * LOG2E);
        u.y = cvt_pk_bf16(acc[2] * LOG2E, acc[3] * LOG2E);
        u.z = cvt_pk_bf16(acc[4] * LOG2E, acc[5] * LOG2E);
        u.w = cvt_pk_bf16(acc[6] * LOG2E, acc[7] * LOG2E);
        __hip_bfloat16* tp = theta16 + ((size_t)b * HW + q) * 16;
        *(uint4*)(tp)     = u;
        *(uint4*)(tp + 8) = z;
    }

    #pragma unroll
    for (int oc = 0; oc < 40; ++oc) conv_lds[t * 41 + oc] = acc[8 + oc];
    __syncthreads();

    for (int wi = t; wi < 40 * 64; wi += 256) {
        const int oc = wi >> 6;
        const int kl = wi & 63;
        const int pr = kl >> 5, pc = kl & 31;
        const int i00 = (2 * pr) * 64 + 2 * pc;
        const float v0 = conv_lds[(i00)      * 41 + oc];
        const float v1 = conv_lds[(i00 + 1)  * 41 + oc];
        const float v2 = conv_lds[(i00 + 64) * 41 + oc];
        const float v3 = conv_lds[(i00 + 65) * 41 + oc];
        const float v  = fmaxf(fmaxf(v0, v1), fmaxf(v2, v3));
        const int kg = (2 * rg + pr) * 32 + pc;
        if (oc < 8) phi16[((size_t)b * KP + kg) * 16 + oc] = __float2bfloat16(v);
        else        gT[((size_t)b * 32 + (oc - 8)) * KP + kg] = __float2bfloat16(v);
    }
    // zero-pad phi upper 8 channels (64 pooled rows this block produced live
    // anywhere; just pad the whole batch cooperatively: 1024 rows / 256 blocks
    // of this batch... each block pads its own 64 rows)
    {
        uint4 z = {0u, 0u, 0u, 0u};
        for (int wi = t; wi < 64; wi += 256) {
            const int kg = 2 * rg * 32 + wi;   // the 64 pooled rows of this block
            *(uint4*)(phi16 + ((size_t)b * KP + kg) * 16 + 8) = z;
        }
    }
}

// ---------------------------------------------------------------------------
// Kernel B: MFMA flash attention + w_o conv + residual.
// Grid 256 blocks (16/batch, 256 queries), 512 threads = 8 waves.
// Wave w: K-half h = w>>2 (keys 512h..512h+511), q-pair qp = w&3
// (q-tiles 64qp and 64qp+32). Partial (O,l) combined additively via LDS.
// ---------------------------------------------------------------------------
__global__ __launch_bounds__(512, 2) void attn_kernel(
    const float* __restrict__ x,
    const float* __restrict__ w_o,
    const float* __restrict__ gamma_p,
    const __hip_bfloat16* __restrict__ theta16,
    const __hip_bfloat16* __restrict__ phi16,
    const __hip_bfloat16* __restrict__ gT,
    float* __restrict__ out)
{
    __shared__ __align__(16) char lds[LDS_BYTES];
    const int t = threadIdx.x;
    // XCD-aware swizzle: 256 blocks = 8 XCDs x 32; keep a batch's 16 blocks
    // on one XCD so its 1.5MB phi/g/theta set is L2-resident per XCD.
    const int bid = (blockIdx.x & 7) * 32 + (blockIdx.x >> 3);
    const int b   = bid >> 4;
    const int qb0 = (bid & 15) * 256;

    // ---- stage g rows (+16B pad) : 4096 granules / 512 thr ----
    {
        const uint4* src = (const uint4*)(gT + (size_t)b * 32 * KP);
        #pragma unroll
        for (int i = 0; i < 8; ++i) {
            const int gi = t + 512 * i;
            const int c = gi >> 7, kk = gi & 127;
            *(uint4*)(lds + c * G_ROW + kk * 16) = src[gi];
        }
    }
    // ---- stage w_o as bf16 padded rows ----
    if (t < 256) {
        const int co = t >> 2, part = t & 3;
        const float4* wsrc = (const float4*)(w_o + co * 32 + part * 8);
        const float4 f0 = wsrc[0], f1 = wsrc[1];
        uint4 u;
        u.x = cvt_pk_bf16(f0.x, f0.y); u.y = cvt_pk_bf16(f0.z, f0.w);
        u.z = cvt_pk_bf16(f1.x, f1.y); u.w = cvt_pk_bf16(f1.z, f1.w);
        *(uint4*)(lds + WO_OFF + co * WO_ROW + part * 16) = u;
    }
    __syncthreads();

    const int lane = t & 63;
    const int wv   = t >> 6;
    const int h    = wv >> 2;          // K-half
    const int qp   = wv & 3;           // q-pair
    const int hi   = lane >> 5;
    const int ln   = lane & 31;
    const int qt0  = qp * 64, qt1 = qt0 + 32;
    const int kbase = h * 512;

    // loop-invariant theta B-fragments (global, coalesced 1KB/frag)
    const uint4* thb = (const uint4*)(theta16 + ((size_t)b * HW + qb0) * 16);
    Frag bth0, bth1;
    bth0.u = thb[(qt0 + ln) * 2 + hi];
    bth1.u = thb[(qt1 + ln) * 2 + hi];

    const uint4* phb = (const uint4*)(phi16 + ((size_t)b * KP + kbase) * 16);
    const char*  gp  = lds + ln * G_ROW + kbase * 2 + hi * 16;

    floatx16 czero = {};
    floatx16 O0 = {}, O1 = {};
    float l0 = 0.f, l1 = 0.f;

    #pragma unroll 2
    for (int kb = 0; kb < 16; ++kb) {
        Frag aphi, gf0, gf1;
        aphi.u = phb[(kb * 32 + ln) * 2 + hi];
        gf0.u  = *(const uint4*)(gp + kb * 64);
        gf1.u  = *(const uint4*)(gp + kb * 64 + 32);

        floatx16 S0 = __builtin_amdgcn_mfma_f32_32x32x16_bf16(aphi.s, bth0.s, czero, 0, 0, 0);
        floatx16 S1 = __builtin_amdgcn_mfma_f32_32x32x16_bf16(aphi.s, bth1.s, czero, 0, 0, 0);

        float p0[16], p1[16];
        float la = 0.f, lb = 0.f, lc = 0.f, ld = 0.f;
        #pragma unroll
        for (int r = 0; r < 16; r += 2) {
            p0[r]   = __builtin_amdgcn_exp2f(S0[r]);   la += p0[r];
            p0[r+1] = __builtin_amdgcn_exp2f(S0[r+1]); lb += p0[r+1];
        }
        #pragma unroll
        for (int r = 0; r < 16; r += 2) {
            p1[r]   = __builtin_amdgcn_exp2f(S1[r]);   lc += p1[r];
            p1[r+1] = __builtin_amdgcn_exp2f(S1[r+1]); ld += p1[r+1];
        }
        l0 += la + lb; l1 += lc + ld;

        Frag pa00, pa01, pa10, pa11;
        build_pfrags(p0, pa00, pa01);
        build_pfrags(p1, pa10, pa11);

        O0 = __builtin_amdgcn_mfma_f32_32x32x16_bf16(pa00.s, gf0.s, O0, 0, 0, 0);
        O0 = __builtin_amdgcn_mfma_f32_32x32x16_bf16(pa01.s, gf1.s, O0, 0, 0, 0);
        O1 = __builtin_amdgcn_mfma_f32_32x32x16_bf16(pa10.s, gf0.s, O1, 0, 0, 0);
        O1 = __builtin_amdgcn_mfma_f32_32x32x16_bf16(pa11.s, gf1.s, O1, 0, 0, 0);
    }

    __syncthreads();   // all g reads done; O-partials may now overwrite G region

    // write O-partials (rows = local q, cols = c = ln) and l-partials
    #pragma unroll
    for (int r = 0; r < 16; ++r) {
        const int rr = (r & 3) + 8 * (r >> 2) + 4 * hi;
        *(float*)(lds + ((h << 8) + qt0 + rr) * ATTN_ROW + ln * 4) = O0[r];
        *(float*)(lds + ((h << 8) + qt1 + rr) * ATTN_ROW + ln * 4) = O1[r];
    }
    const float l0t = l0 + __shfl_xor(l0, 32, 64);
    const float l1t = l1 + __shfl_xor(l1, 32, 64);
    {
        const int   lq = hi ? (qt1 + ln) : (qt0 + ln);
        const float lw = hi ? l1t : l0t;
        *(float*)(lds + L_OFF + ((h << 8) + lq) * 4) = lw;
    }
    __syncthreads();

    // ---- epilogue: wave wv handles q-tile qt = 32*wv ----
    const float gam = gamma_p[0];
    const int   qt  = wv * 32;
    const float lt  = *(const float*)(lds + L_OFF + (qt + ln) * 4)
                    + *(const float*)(lds + L_OFF + (256 + qt + ln) * 4);
    const float gl  = gam / lt;

    const char* ab0 = lds + (qt + ln) * ATTN_ROW + hi * 32;
    const char* ab1 = ab0 + 256 * ATTN_ROW;
    float4 a0 = *(const float4*)(ab0);
    float4 a1 = *(const float4*)(ab0 + 16);
    float4 a2 = *(const float4*)(ab0 + 64);
    float4 a3 = *(const float4*)(ab0 + 80);
    const float4 c0 = *(const float4*)(ab1);
    const float4 c1 = *(const float4*)(ab1 + 16);
    const float4 c2 = *(const float4*)(ab1 + 64);
    const float4 c3 = *(const float4*)(ab1 + 80);
    a0.x += c0.x; a0.y += c0.y; a0.z += c0.z; a0.w += c0.w;
    a1.x += c1.x; a1.y += c1.y; a1.z += c1.z; a1.w += c1.w;
    a2.x += c2.x; a2.y += c2.y; a2.z += c2.z; a2.w += c2.w;
    a3.x += c3.x; a3.y += c3.y; a3.z += c3.z; a3.w += c3.w;

    Frag bat0, bat1;
    bat0.u.x = cvt_pk_bf16(a0.x, a0.y); bat0.u.y = cvt_pk_bf16(a0.z, a0.w);
    bat0.u.z = cvt_pk_bf16(a1.x, a1.y); bat0.u.w = cvt_pk_bf16(a1.z, a1.w);
    bat1.u.x = cvt_pk_bf16(a2.x, a2.y); bat1.u.y = cvt_pk_bf16(a2.z, a2.w);
    bat1.u.z = cvt_pk_bf16(a3.x, a3.y); bat1.u.w = cvt_pk_bf16(a3.z, a3.w);

    const char* wb = lds + WO_OFF + ln * WO_ROW + hi * 16;
    Frag wa00, wa01, wa10, wa11;
    wa00.u = *(const uint4*)(wb);
    wa01.u = *(const uint4*)(wb + 32);
    wa10.u = *(const uint4*)(wb + 32 * WO_ROW);
    wa11.u = *(const uint4*)(wb + 32 * WO_ROW + 32);

    floatx16 D0 = __builtin_amdgcn_mfma_f32_32x32x16_bf16(wa00.s, bat0.s, czero, 0, 0, 0);
    D0 = __builtin_amdgcn_mfma_f32_32x32x16_bf16(wa01.s, bat1.s, D0, 0, 0, 0);
    floatx16 D1 = __builtin_amdgcn_mfma_f32_32x32x16_bf16(wa10.s, bat0.s, czero, 0, 0, 0);
    D1 = __builtin_amdgcn_mfma_f32_32x32x16_bf16(wa11.s, bat1.s, D1, 0, 0, 0);

    const int qg = qb0 + qt + ln;
    const float* xb = x   + (size_t)b * C_ * HW + qg;
    float*       ob = out + (size_t)b * C_ * HW + qg;
    #pragma unroll
    for (int r = 0; r < 16; ++r) {
        const int co = (r & 3) + 8 * (r >> 2) + 4 * hi;
        ob[(size_t)co * HW]        = xb[(size_t)co * HW]        + gl * D0[r];
        ob[(size_t)(co + 32) * HW] = xb[(size_t)(co + 32) * HW] + gl * D1[r];
    }
}

extern "C" void kernel_launch(void* const* d_in, const int* in_sizes, int n_in,
                              void* d_out, int out_size, void* d_ws, size_t ws_size,
                              hipStream_t stream) {
    const float* x       = (const float*)d_in[0];
    const float* w_theta = (const float*)d_in[1];
    const float* w_phi   = (const float*)d_in[2];
    const float* w_g     = (const float*)d_in[3];
    const float* w_o     = (const float*)d_in[4];
    const float* gamma   = (const float*)d_in[5];
    float* out = (float*)d_out;

    __hip_bfloat16* theta16 = (__hip_bfloat16*)d_ws;                 // 16*4096*16 bf16 = 2 MB
    __hip_bfloat16* phi16   = theta16 + (size_t)B_ * HW * 16;        // 16*1024*16 bf16 = 512 KB
    __hip_bfloat16* gT      = phi16   + (size_t)B_ * KP * 16;        // 16*32*1024 bf16 = 1 MB

    convpool_kernel<<<dim3(B_ * 16), dim3(256), 0, stream>>>(
        x, w_theta, w_phi, w_g, theta16, phi16, gT);
    attn_kernel<<<dim3(B_ * 16), dim3(512), 0, stream>>>(
        x, w_o, gamma, theta16, phi16, gT, out);
}

// Round 4
// 30.933 us; speedup vs baseline: 2.4469x; 2.4469x over previous
//
#include <hip/hip_runtime.h>
#include <hip/hip_bf16.h>

#define B_  16
#define C_  64
#define HW  4096   // 64*64
#define KP  1024   // pooled positions (32*32)
#define LOG2E 1.44269504088896f

typedef short short8 __attribute__((ext_vector_type(8)));
typedef float floatx16 __attribute__((ext_vector_type(16)));

union Frag { uint4 u; short8 s; };

// ---- attn kernel LDS layout (bytes) ----
#define G_ROW      2064
#define ATTN_ROW   144
#define UNION_SZ   73728
#define WO_OFF     UNION_SZ
#define WO_ROW     80
#define L_OFF      (WO_OFF + 5120)
#define LDS_BYTES  (L_OFF + 2048)      // 80896

__device__ __forceinline__ unsigned cvt_pk_bf16(float lo, float hi) {
    unsigned r;
    asm("v_cvt_pk_bf16_f32 %0, %1, %2" : "=v"(r) : "v"(lo), "v"(hi));
    return r;
}
#define PLSWAP(a, b) asm("v_permlane32_swap_b32 %0, %1" : "+v"(a), "+v"(b))

// Build two PV A-operand fragments (K=16 each) from 16 lane-local P values.
__device__ __forceinline__ void build_pfrags(const float* p, Frag& f0, Frag& f1) {
    unsigned u0 = cvt_pk_bf16(p[0], p[1]);
    unsigned u1 = cvt_pk_bf16(p[2], p[3]);
    unsigned u2 = cvt_pk_bf16(p[4], p[5]);
    unsigned u3 = cvt_pk_bf16(p[6], p[7]);
    PLSWAP(u0, u2);
    PLSWAP(u1, u3);
    f0.u.x = u0; f0.u.y = u1; f0.u.z = u2; f0.u.w = u3;
    unsigned v0 = cvt_pk_bf16(p[8],  p[9]);
    unsigned v1 = cvt_pk_bf16(p[10], p[11]);
    unsigned v2 = cvt_pk_bf16(p[12], p[13]);
    unsigned v3 = cvt_pk_bf16(p[14], p[15]);
    PLSWAP(v0, v2);
    PLSWAP(v1, v3);
    f1.u.x = v0; f1.u.y = v1; f1.u.z = v2; f1.u.w = v3;
}

// ---------------------------------------------------------------------------
// Kernel A (v2): MFMA 1x1 conv (48 oc = theta(8) ++ phi(8) ++ g(32)) + pool.
// Block = 256 threads = 256 px (4 image rows). Each thread loads its pixel's
// 64 channels once (coalesced); A-fragments built in-register via PLSWAP;
// weights read once per lane as B-fragments. Conv -> LDS[48][257] -> theta
// store (full-res) + 2x2 maxpool for phi/g. No per-c weight loads.
// ---------------------------------------------------------------------------
__global__ __launch_bounds__(256) void convpool_kernel(
    const float* __restrict__ x,
    const float* __restrict__ w_theta,
    const float* __restrict__ w_phi,
    const float* __restrict__ w_g,
    __hip_bfloat16* __restrict__ theta16,
    __hip_bfloat16* __restrict__ phi16,
    __hip_bfloat16* __restrict__ gT)
{
    __shared__ float conv[48 * 257];   // [oc][px], stride 257 -> conflict-free
    const int bi = blockIdx.x;
    const int b  = bi >> 4;
    const int rg = bi & 15;
    const int t  = threadIdx.x;
    const int q  = rg * 256 + t;

    const float* xb = x + (size_t)b * C_ * HW + q;

    // ---- load this pixel's 64 channels (coalesced, 64-deep MLP), pack bf16x2
    float xv[64];
    #pragma unroll
    for (int c = 0; c < C_; ++c) xv[c] = xb[(size_t)c * HW];
    unsigned r[32];
    #pragma unroll
    for (int i = 0; i < 32; ++i) r[i] = cvt_pk_bf16(xv[2 * i], xv[2 * i + 1]);

    const int lane = t & 63;
    const int ln   = lane & 31;
    const int hi   = lane >> 5;
    const int wv   = t >> 6;

    // ---- B-fragments: weight rows, oc order theta(0-7) phi(8-15) g(16-47)
    const float* wrow0 = (ln < 8)  ? (w_theta + ln * C_)
                       : (ln < 16) ? (w_phi + (ln - 8) * C_)
                                   : (w_g + (ln - 16) * C_);
    const float* wrow1 = (ln < 16) ? (w_g + (16 + ln) * C_) : (w_g + 31 * C_);

    Frag B0[4], B1[4];
    #pragma unroll
    for (int k = 0; k < 4; ++k) {
        const float* p0 = wrow0 + 16 * k + 8 * hi;
        const float4 f0 = *(const float4*)(p0);
        const float4 f1 = *(const float4*)(p0 + 4);
        B0[k].u.x = cvt_pk_bf16(f0.x, f0.y); B0[k].u.y = cvt_pk_bf16(f0.z, f0.w);
        B0[k].u.z = cvt_pk_bf16(f1.x, f1.y); B0[k].u.w = cvt_pk_bf16(f1.z, f1.w);
        const float* p1 = wrow1 + 16 * k + 8 * hi;
        const float4 g0 = *(const float4*)(p1);
        const float4 g1 = *(const float4*)(p1 + 4);
        B1[k].u.x = cvt_pk_bf16(g0.x, g0.y); B1[k].u.y = cvt_pk_bf16(g0.z, g0.w);
        B1[k].u.z = cvt_pk_bf16(g1.x, g1.y); B1[k].u.w = cvt_pk_bf16(g1.z, g1.w);
    }

    // ---- conv: D[px-tile][oc-tile], A-frags via PLSWAP (px lo/hi tiles)
    floatx16 D00 = {}, D01 = {}, D10 = {}, D11 = {};
    #pragma unroll
    for (int k = 0; k < 4; ++k) {
        unsigned a0 = r[8*k+0], a1 = r[8*k+1], a2 = r[8*k+2], a3 = r[8*k+3];
        unsigned b0 = r[8*k+4], b1 = r[8*k+5], b2 = r[8*k+6], b3 = r[8*k+7];
        PLSWAP(a0, b0); PLSWAP(a1, b1); PLSWAP(a2, b2); PLSWAP(a3, b3);
        Frag loF, hiF;
        loF.u.x = a0; loF.u.y = a1; loF.u.z = a2; loF.u.w = a3;
        hiF.u.x = b0; hiF.u.y = b1; hiF.u.z = b2; hiF.u.w = b3;
        D00 = __builtin_amdgcn_mfma_f32_32x32x16_bf16(loF.s, B0[k].s, D00, 0, 0, 0);
        D01 = __builtin_amdgcn_mfma_f32_32x32x16_bf16(loF.s, B1[k].s, D01, 0, 0, 0);
        D10 = __builtin_amdgcn_mfma_f32_32x32x16_bf16(hiF.s, B0[k].s, D10, 0, 0, 0);
        D11 = __builtin_amdgcn_mfma_f32_32x32x16_bf16(hiF.s, B1[k].s, D11, 0, 0, 0);
    }

    // ---- write conv results to LDS: D col = oc (lane), row = px-in-tile
    #pragma unroll
    for (int rI = 0; rI < 16; ++rI) {
        const int row = (rI & 3) + 8 * (rI >> 2) + 4 * hi;
        conv[ln * 257 + (wv * 64 + row)]      = D00[rI];
        conv[ln * 257 + (wv * 64 + 32 + row)] = D10[rI];
        if (ln < 16) {
            conv[(32 + ln) * 257 + (wv * 64 + row)]      = D01[rI];
            conv[(32 + ln) * 257 + (wv * 64 + 32 + row)] = D11[rI];
        }
    }
    __syncthreads();

    // ---- theta out: full-res, x LOG2E, K-padded to 16
    {
        float th[8];
        #pragma unroll
        for (int oc = 0; oc < 8; ++oc) th[oc] = conv[oc * 257 + t] * LOG2E;
        uint4 u, z = {0u, 0u, 0u, 0u};
        u.x = cvt_pk_bf16(th[0], th[1]);
        u.y = cvt_pk_bf16(th[2], th[3]);
        u.z = cvt_pk_bf16(th[4], th[5]);
        u.w = cvt_pk_bf16(th[6], th[7]);
        __hip_bfloat16* tp = theta16 + ((size_t)b * HW + q) * 16;
        *(uint4*)(tp)     = u;
        *(uint4*)(tp + 8) = z;
    }

    // ---- 2x2 maxpool for phi (conv oc 8-15) and g (conv oc 16-47)
    for (int wi = t; wi < 40 * 64; wi += 256) {
        const int oc = (wi >> 6) + 8;
        const int kl = wi & 63;
        const int pr = kl >> 5, pc = kl & 31;
        const int i00 = pr * 128 + pc * 2;
        const float* cp = conv + oc * 257;
        const float v = fmaxf(fmaxf(cp[i00], cp[i00 + 1]),
                              fmaxf(cp[i00 + 64], cp[i00 + 65]));
        const int kg = (2 * rg + pr) * 32 + pc;
        if (oc < 16) phi16[((size_t)b * KP + kg) * 16 + (oc - 8)] = __float2bfloat16(v);
        else         gT[((size_t)b * 32 + (oc - 16)) * KP + kg]   = __float2bfloat16(v);
    }
    // pad phi upper 8 channels for this block's 64 pooled rows
    {
        uint4 z = {0u, 0u, 0u, 0u};
        for (int wi = t; wi < 64; wi += 256) {
            const int kg = 2 * rg * 32 + wi;
            *(uint4*)(phi16 + ((size_t)b * KP + kg) * 16 + 8) = z;
        }
    }
}

// ---------------------------------------------------------------------------
// Kernel B: MFMA flash attention + w_o conv + residual (unchanged, round 3).
// ---------------------------------------------------------------------------
__global__ __launch_bounds__(512, 2) void attn_kernel(
    const float* __restrict__ x,
    const float* __restrict__ w_o,
    const float* __restrict__ gamma_p,
    const __hip_bfloat16* __restrict__ theta16,
    const __hip_bfloat16* __restrict__ phi16,
    const __hip_bfloat16* __restrict__ gT,
    float* __restrict__ out)
{
    __shared__ __align__(16) char lds[LDS_BYTES];
    const int t = threadIdx.x;
    const int bid = (blockIdx.x & 7) * 32 + (blockIdx.x >> 3);
    const int b   = bid >> 4;
    const int qb0 = (bid & 15) * 256;

    {
        const uint4* src = (const uint4*)(gT + (size_t)b * 32 * KP);
        #pragma unroll
        for (int i = 0; i < 8; ++i) {
            const int gi = t + 512 * i;
            const int c = gi >> 7, kk = gi & 127;
            *(uint4*)(lds + c * G_ROW + kk * 16) = src[gi];
        }
    }
    if (t < 256) {
        const int co = t >> 2, part = t & 3;
        const float4* wsrc = (const float4*)(w_o + co * 32 + part * 8);
        const float4 f0 = wsrc[0], f1 = wsrc[1];
        uint4 u;
        u.x = cvt_pk_bf16(f0.x, f0.y); u.y = cvt_pk_bf16(f0.z, f0.w);
        u.z = cvt_pk_bf16(f1.x, f1.y); u.w = cvt_pk_bf16(f1.z, f1.w);
        *(uint4*)(lds + WO_OFF + co * WO_ROW + part * 16) = u;
    }
    __syncthreads();

    const int lane = t & 63;
    const int wv   = t >> 6;
    const int h    = wv >> 2;
    const int qp   = wv & 3;
    const int hi   = lane >> 5;
    const int ln   = lane & 31;
    const int qt0  = qp * 64, qt1 = qt0 + 32;
    const int kbase = h * 512;

    const uint4* thb = (const uint4*)(theta16 + ((size_t)b * HW + qb0) * 16);
    Frag bth0, bth1;
    bth0.u = thb[(qt0 + ln) * 2 + hi];
    bth1.u = thb[(qt1 + ln) * 2 + hi];

    const uint4* phb = (const uint4*)(phi16 + ((size_t)b * KP + kbase) * 16);
    const char*  gp  = lds + ln * G_ROW + kbase * 2 + hi * 16;

    floatx16 czero = {};
    floatx16 O0 = {}, O1 = {};
    float l0 = 0.f, l1 = 0.f;

    #pragma unroll 2
    for (int kb = 0; kb < 16; ++kb) {
        Frag aphi, gf0, gf1;
        aphi.u = phb[(kb * 32 + ln) * 2 + hi];
        gf0.u  = *(const uint4*)(gp + kb * 64);
        gf1.u  = *(const uint4*)(gp + kb * 64 + 32);

        floatx16 S0 = __builtin_amdgcn_mfma_f32_32x32x16_bf16(aphi.s, bth0.s, czero, 0, 0, 0);
        floatx16 S1 = __builtin_amdgcn_mfma_f32_32x32x16_bf16(aphi.s, bth1.s, czero, 0, 0, 0);

        float p0[16], p1[16];
        float la = 0.f, lb = 0.f, lc = 0.f, ld = 0.f;
        #pragma unroll
        for (int rr = 0; rr < 16; rr += 2) {
            p0[rr]   = __builtin_amdgcn_exp2f(S0[rr]);   la += p0[rr];
            p0[rr+1] = __builtin_amdgcn_exp2f(S0[rr+1]); lb += p0[rr+1];
        }
        #pragma unroll
        for (int rr = 0; rr < 16; rr += 2) {
            p1[rr]   = __builtin_amdgcn_exp2f(S1[rr]);   lc += p1[rr];
            p1[rr+1] = __builtin_amdgcn_exp2f(S1[rr+1]); ld += p1[rr+1];
        }
        l0 += la + lb; l1 += lc + ld;

        Frag pa00, pa01, pa10, pa11;
        build_pfrags(p0, pa00, pa01);
        build_pfrags(p1, pa10, pa11);

        O0 = __builtin_amdgcn_mfma_f32_32x32x16_bf16(pa00.s, gf0.s, O0, 0, 0, 0);
        O0 = __builtin_amdgcn_mfma_f32_32x32x16_bf16(pa01.s, gf1.s, O0, 0, 0, 0);
        O1 = __builtin_amdgcn_mfma_f32_32x32x16_bf16(pa10.s, gf0.s, O1, 0, 0, 0);
        O1 = __builtin_amdgcn_mfma_f32_32x32x16_bf16(pa11.s, gf1.s, O1, 0, 0, 0);
    }

    __syncthreads();

    #pragma unroll
    for (int rr = 0; rr < 16; ++rr) {
        const int rm = (rr & 3) + 8 * (rr >> 2) + 4 * hi;
        *(float*)(lds + ((h << 8) + qt0 + rm) * ATTN_ROW + ln * 4) = O0[rr];
        *(float*)(lds + ((h << 8) + qt1 + rm) * ATTN_ROW + ln * 4) = O1[rr];
    }
    const float l0t = l0 + __shfl_xor(l0, 32, 64);
    const float l1t = l1 + __shfl_xor(l1, 32, 64);
    {
        const int   lq = hi ? (qt1 + ln) : (qt0 + ln);
        const float lw = hi ? l1t : l0t;
        *(float*)(lds + L_OFF + ((h << 8) + lq) * 4) = lw;
    }
    __syncthreads();

    const float gam = gamma_p[0];
    const int   qt  = wv * 32;
    const float lt  = *(const float*)(lds + L_OFF + (qt + ln) * 4)
                    + *(const float*)(lds + L_OFF + (256 + qt + ln) * 4);
    const float gl  = gam / lt;

    const char* ab0 = lds + (qt + ln) * ATTN_ROW + hi * 32;
    const char* ab1 = ab0 + 256 * ATTN_ROW;
    float4 a0 = *(const float4*)(ab0);
    float4 a1 = *(const float4*)(ab0 + 16);
    float4 a2 = *(const float4*)(ab0 + 64);
    float4 a3 = *(const float4*)(ab0 + 80);
    const float4 c0 = *(const float4*)(ab1);
    const float4 c1 = *(const float4*)(ab1 + 16);
    const float4 c2 = *(const float4*)(ab1 + 64);
    const float4 c3 = *(const float4*)(ab1 + 80);
    a0.x += c0.x; a0.y += c0.y; a0.z += c0.z; a0.w += c0.w;
    a1.x += c1.x; a1.y += c1.y; a1.z += c1.z; a1.w += c1.w;
    a2.x += c2.x; a2.y += c2.y; a2.z += c2.z; a2.w += c2.w;
    a3.x += c3.x; a3.y += c3.y; a3.z += c3.z; a3.w += c3.w;

    Frag bat0, bat1;
    bat0.u.x = cvt_pk_bf16(a0.x, a0.y); bat0.u.y = cvt_pk_bf16(a0.z, a0.w);
    bat0.u.z = cvt_pk_bf16(a1.x, a1.y); bat0.u.w = cvt_pk_bf16(a1.z, a1.w);
    bat1.u.x = cvt_pk_bf16(a2.x, a2.y); bat1.u.y = cvt_pk_bf16(a2.z, a2.w);
    bat1.u.z = cvt_pk_bf16(a3.x, a3.y); bat1.u.w = cvt_pk_bf16(a3.z, a3.w);

    const char* wb = lds + WO_OFF + ln * WO_ROW + hi * 16;
    Frag wa00, wa01, wa10, wa11;
    wa00.u = *(const uint4*)(wb);
    wa01.u = *(const uint4*)(wb + 32);
    wa10.u = *(const uint4*)(wb + 32 * WO_ROW);
    wa11.u = *(const uint4*)(wb + 32 * WO_ROW + 32);

    floatx16 D0 = __builtin_amdgcn_mfma_f32_32x32x16_bf16(wa00.s, bat0.s, czero, 0, 0, 0);
    D0 = __builtin_amdgcn_mfma_f32_32x32x16_bf16(wa01.s, bat1.s, D0, 0, 0, 0);
    floatx16 D1 = __builtin_amdgcn_mfma_f32_32x32x16_bf16(wa10.s, bat0.s, czero, 0, 0, 0);
    D1 = __builtin_amdgcn_mfma_f32_32x32x16_bf16(wa11.s, bat1.s, D1, 0, 0, 0);

    const int qg = qb0 + qt + ln;
    const float* xb = x   + (size_t)b * C_ * HW + qg;
    float*       ob = out + (size_t)b * C_ * HW + qg;
    #pragma unroll
    for (int rr = 0; rr < 16; ++rr) {
        const int co = (rr & 3) + 8 * (rr >> 2) + 4 * hi;
        ob[(size_t)co * HW]        = xb[(size_t)co * HW]        + gl * D0[rr];
        ob[(size_t)(co + 32) * HW] = xb[(size_t)(co + 32) * HW] + gl * D1[rr];
    }
}

extern "C" void kernel_launch(void* const* d_in, const int* in_sizes, int n_in,
                              void* d_out, int out_size, void* d_ws, size_t ws_size,
                              hipStream_t stream) {
    const float* x       = (const float*)d_in[0];
    const float* w_theta = (const float*)d_in[1];
    const float* w_phi   = (const float*)d_in[2];
    const float* w_g     = (const float*)d_in[3];
    const float* w_o     = (const float*)d_in[4];
    const float* gamma   = (const float*)d_in[5];
    float* out = (float*)d_out;

    __hip_bfloat16* theta16 = (__hip_bfloat16*)d_ws;                 // 2 MB
    __hip_bfloat16* phi16   = theta16 + (size_t)B_ * HW * 16;        // 512 KB
    __hip_bfloat16* gT      = phi16   + (size_t)B_ * KP * 16;        // 1 MB

    convpool_kernel<<<dim3(B_ * 16), dim3(256), 0, stream>>>(
        x, w_theta, w_phi, w_g, theta16, phi16, gT);
    attn_kernel<<<dim3(B_ * 16), dim3(512), 0, stream>>>(
        x, w_o, gamma, theta16, phi16, gT, out);
}